// Round 1
// baseline (85.206 us; speedup 1.0000x reference)
//
#include <hip/hip_runtime.h>

#define D 2048
#define RANK 16
#define ROWS_PER_BLOCK 32
#define NTHREADS 512

__global__ __launch_bounds__(NTHREADS, 2)
void lora_fused_kernel(const float* __restrict__ h,
                       const float* __restrict__ A,
                       const float* __restrict__ B,
                       float* __restrict__ out) {
    const int tid  = threadIdx.x;
    const int dg   = tid & 127;    // d-group: 0..127
    const int rg   = tid >> 7;     // rank-quad: 0..3
    const int wave = tid >> 6;     // 0..7 (rg = wave>>1)
    const int lane = tid & 63;
    const long row0 = (long)blockIdx.x * ROWS_PER_BLOCK;

    // ---- Preload B fragments (once per block, reused for 32 rows) ----
    // Bf[r'][c] = B[(rg*4+r')*D + c*512 + dg*4 .. +3]
    float4 Bf[4][4];
#pragma unroll
    for (int r = 0; r < 4; ++r)
#pragma unroll
        for (int c = 0; c < 4; ++c)
            Bf[r][c] = *reinterpret_cast<const float4*>(
                &B[(rg * 4 + r) * D + c * 512 + dg * 4]);

    // ---- Preload A rows for this thread's 4 output columns e = tid*4+j ----
    // Af[j][q] = A[(tid*4+j)*RANK + q*4 .. +3]
    float4 Af[4][4];
#pragma unroll
    for (int j = 0; j < 4; ++j)
#pragma unroll
        for (int q = 0; q < 4; ++q)
            Af[j][q] = *reinterpret_cast<const float4*>(
                &A[(tid * 4 + j) * RANK + q * 4]);

    // double-buffered per-wave rank partials
    __shared__ float4 lds_part[2][8];

    const int dbase = dg * 4;  // + c*512

    // ---- phase1 for row0 into buffer 0 ----
    float4 hn[4];
#pragma unroll
    for (int c = 0; c < 4; ++c)
        hn[c] = *reinterpret_cast<const float4*>(&h[row0 * D + c * 512 + dbase]);
    {
        float acc[4] = {0.f, 0.f, 0.f, 0.f};
#pragma unroll
        for (int r = 0; r < 4; ++r)
#pragma unroll
            for (int c = 0; c < 4; ++c) {
                acc[r] += hn[c].x * Bf[r][c].x + hn[c].y * Bf[r][c].y +
                          hn[c].z * Bf[r][c].z + hn[c].w * Bf[r][c].w;
            }
#pragma unroll
        for (int m = 1; m < 64; m <<= 1)
#pragma unroll
            for (int r = 0; r < 4; ++r)
                acc[r] += __shfl_xor(acc[r], m, 64);
        if (lane == 0)
            lds_part[0][wave] = make_float4(acc[0], acc[1], acc[2], acc[3]);
    }
    // prefetch row1
    if (ROWS_PER_BLOCK > 1) {
#pragma unroll
        for (int c = 0; c < 4; ++c)
            hn[c] = *reinterpret_cast<const float4*>(
                &h[(row0 + 1) * D + c * 512 + dbase]);
    }
    __syncthreads();

    for (int i = 0; i < ROWS_PER_BLOCK; ++i) {
        const int buf = i & 1;

        // prefetch h(row i+2)
        float4 hn2[4];
        if (i + 2 < ROWS_PER_BLOCK) {
#pragma unroll
            for (int c = 0; c < 4; ++c)
                hn2[c] = *reinterpret_cast<const float4*>(
                    &h[(row0 + i + 2) * D + c * 512 + dbase]);
        }

        // ---- phase1 for row i+1 (uses hn, in flight since last iter) ----
        if (i + 1 < ROWS_PER_BLOCK) {
            float acc[4] = {0.f, 0.f, 0.f, 0.f};
#pragma unroll
            for (int r = 0; r < 4; ++r)
#pragma unroll
                for (int c = 0; c < 4; ++c) {
                    acc[r] += hn[c].x * Bf[r][c].x + hn[c].y * Bf[r][c].y +
                              hn[c].z * Bf[r][c].z + hn[c].w * Bf[r][c].w;
                }
#pragma unroll
            for (int m = 1; m < 64; m <<= 1)
#pragma unroll
                for (int r = 0; r < 4; ++r)
                    acc[r] += __shfl_xor(acc[r], m, 64);
            if (lane == 0)
                lds_part[buf ^ 1][wave] =
                    make_float4(acc[0], acc[1], acc[2], acc[3]);
        }

        // ---- phase2 for row i (reads buffer written last iteration) ----
        {
            float4 tq[4];
#pragma unroll
            for (int q = 0; q < 4; ++q) {
                float4 p0 = lds_part[buf][2 * q];
                float4 p1 = lds_part[buf][2 * q + 1];
                tq[q] = make_float4(p0.x + p1.x, p0.y + p1.y, p0.z + p1.z,
                                    p0.w + p1.w);
            }
            float res[4];
#pragma unroll
            for (int j = 0; j < 4; ++j) {
                float v = 0.f;
#pragma unroll
                for (int q = 0; q < 4; ++q) {
                    v += tq[q].x * Af[j][q].x + tq[q].y * Af[j][q].y +
                         tq[q].z * Af[j][q].z + tq[q].w * Af[j][q].w;
                }
                res[j] = v;
            }
            *reinterpret_cast<float4*>(&out[(row0 + i) * D + tid * 4]) =
                make_float4(res[0], res[1], res[2], res[3]);
        }

        __syncthreads();
#pragma unroll
        for (int c = 0; c < 4; ++c) hn[c] = hn2[c];
    }
}

extern "C" void kernel_launch(void* const* d_in, const int* in_sizes, int n_in,
                              void* d_out, int out_size, void* d_ws,
                              size_t ws_size, hipStream_t stream) {
    const float* h = (const float*)d_in[0];
    const float* A = (const float*)d_in[1];
    const float* B = (const float*)d_in[2];
    float* out = (float*)d_out;

    const int n_rows = in_sizes[0] / D;            // 4*4096 = 16384
    const int blocks = n_rows / ROWS_PER_BLOCK;    // 512

    hipLaunchKernelGGL(lora_fused_kernel, dim3(blocks), dim3(NTHREADS), 0,
                       stream, h, A, B, out);
}